// Round 10
// baseline (209.901 us; speedup 1.0000x reference)
//
#include <hip/hip_runtime.h>
#include <hip/hip_bf16.h>

typedef __bf16 bf16;
typedef __bf16 bf16x8 __attribute__((ext_vector_type(8)));
typedef float f32x4 __attribute__((ext_vector_type(4)));

#define MFMA16(a, b, c) __builtin_amdgcn_mfma_f32_16x16x32_bf16((a), (b), (c), 0, 0, 0)

// async global->LDS, 16B per lane; LDS dest = wave-uniform base + lane*16.
__device__ __forceinline__ void async16(const void* g, void* l) {
  typedef const unsigned int __attribute__((address_space(1))) * GP;
  typedef unsigned int __attribute__((address_space(3))) * LP;
  __builtin_amdgcn_global_load_lds((GP)g, (LP)l, 16, 0, 0);
}

// ---- DPP 16-lane row sum (epilogue only) -----------------------------------
template <int ctrl>
__device__ __forceinline__ float dppf(float v) {
  return __builtin_bit_cast(
      float, __builtin_amdgcn_update_dpp(0, __builtin_bit_cast(int, v), ctrl,
                                         0xf, 0xf, true));
}
__device__ __forceinline__ float rowsum16(float x) {
  x += dppf<0xB1>(x);
  x += dppf<0x4E>(x);
  x += dppf<0x141>(x);
  x += dppf<0x140>(x);
  return x;
}

// ---------------------------------------------------------------------------
// Convert x: fp32 [4M] -> bf16 [4M].
// ---------------------------------------------------------------------------
__global__ __launch_bounds__(256) void convert_x(
    const float* __restrict__ src, bf16* __restrict__ dst) {
  int i = (blockIdx.x * 256 + threadIdx.x) * 4;
  f32x4 v = *(const f32x4*)&src[i];
  bf16 o[4];
#pragma unroll
  for (int j = 0; j < 4; ++j) o[j] = (bf16)v[j];
  *(ulong1*)&dst[i] = *(ulong1*)o;
}

// ---------------------------------------------------------------------------
// Transpose+convert 4 weight matrices fp32 [1024x1024] -> bf16 Wt[n][k].
// ---------------------------------------------------------------------------
__global__ __launch_bounds__(256) void transpose_w(
    const float* __restrict__ w0, const float* __restrict__ w1,
    const float* __restrict__ w2, const float* __restrict__ w3,
    bf16* __restrict__ out) {
  __shared__ __align__(16) float tile[64][68];
  const float* src = (blockIdx.z == 0) ? w0 : (blockIdx.z == 1) ? w1
                   : (blockIdx.z == 2) ? w2 : w3;
  bf16* dst = out + (size_t)blockIdx.z * (1024u * 1024u);
  const int t = threadIdx.x;
  const int bx = blockIdx.x, by = blockIdx.y;

#pragma unroll
  for (int p = 0; p < 4; ++p) {
    int idx = t + p * 256;
    int r = idx >> 4, c4 = idx & 15;
    *(f32x4*)&tile[r][c4 * 4] =
        *(const f32x4*)&src[(size_t)(by * 64 + r) * 1024 + bx * 64 + c4 * 4];
  }
  __syncthreads();
#pragma unroll
  for (int p = 0; p < 2; ++p) {
    int idx = t + p * 256;
    int rn = idx >> 3, c8 = idx & 7;
    bf16x8 v;
#pragma unroll
    for (int i = 0; i < 8; ++i) v[i] = (bf16)tile[c8 * 8 + i][rn];
    *(bf16x8*)&dst[(size_t)(bx * 64 + rn) * 1024 + by * 64 + c8 * 8] = v;
  }
}

// ---------------------------------------------------------------------------
// GEMM: C[M x 1024] = A[M x 1024] @ W (Bt[n][k]). BK=64, DOUBLE-BUFFERED
// global_load_lds staging with ONE barrier per 64-K step (32 MFMA/barrier):
// prefetch k+1 into the alternate buffer, compute k, barrier -> the vmcnt
// drain lands ~540 cyc after prefetch issue (full compute phase), hiding
// L2/L3 latency. XOR swizzle lds[row][cg^(row&7)] -> 2-way reads (free).
// z==0 scaled by scaleZ0 (folds softmax 1/8*log2e into Q).
// z==2 with vtOut != null: write transposed per head into vt[bh][d][s]
// (fuses the V transpose; 4 acc rows -> contiguous s -> 8B stores).
// grid: (N/128, M/128, nz).
// ---------------------------------------------------------------------------
template <typename OutT>
__global__ __launch_bounds__(256, 2) void gemm_bt(
    const bf16* __restrict__ A, const bf16* __restrict__ Bt,
    OutT* __restrict__ C, int btStrideZ, int cStrideZ, float scaleZ0,
    bf16* __restrict__ vtOut) {
  const int tid = threadIdx.x;
  const int wave = tid >> 6, lane = tid & 63;
  const int quad = lane >> 4, l16 = lane & 15;
  const int wm = wave >> 1, wn = wave & 1;
  const int m0 = blockIdx.y * 128, n0 = blockIdx.x * 128;
  const bf16* Bz = Bt + (size_t)blockIdx.z * (size_t)btStrideZ;
  OutT* Cz = C + (size_t)blockIdx.z * (size_t)cStrideZ;
  const float sc = (blockIdx.z == 0) ? scaleZ0 : 1.0f;

  __shared__ __align__(16) bf16 lsA[2][128 * 64];  // 16KB per buf
  __shared__ __align__(16) bf16 lsB[2][128 * 64];

  const int lrow = lane >> 3;         // 0..7 within 8-row chunk
  const int cgX = (lane & 7) ^ lrow;  // swizzled col-group to fetch

  f32x4 acc[4][4];
#pragma unroll
  for (int i = 0; i < 4; ++i)
#pragma unroll
    for (int j = 0; j < 4; ++j) acc[i][j] = (f32x4){0.f, 0.f, 0.f, 0.f};

  // preload K-step 0 into buffer 0
#pragma unroll
  for (int c = 0; c < 4; ++c) {
    int chunk = wave * 4 + c;  // 16 chunks x 8 rows
    int row = chunk * 8 + lrow;
    async16(&A[(size_t)(m0 + row) * 1024 + cgX * 8], &lsA[0][chunk * 512]);
    async16(&Bz[(size_t)(n0 + row) * 1024 + cgX * 8], &lsB[0][chunk * 512]);
  }
  __syncthreads();

  for (int it = 0; it < 16; ++it) {
    const int cur = it & 1;
    if (it < 15) {  // prefetch next 64-K step into the alternate buffer
      int k0n = (it + 1) * 64;
#pragma unroll
      for (int c = 0; c < 4; ++c) {
        int chunk = wave * 4 + c;
        int row = chunk * 8 + lrow;
        async16(&A[(size_t)(m0 + row) * 1024 + k0n + cgX * 8],
                &lsA[cur ^ 1][chunk * 512]);
        async16(&Bz[(size_t)(n0 + row) * 1024 + k0n + cgX * 8],
                &lsB[cur ^ 1][chunk * 512]);
      }
    }

#pragma unroll
    for (int ks = 0; ks < 2; ++ks) {
      bf16x8 af[4], bfr[4];
#pragma unroll
      for (int i = 0; i < 4; ++i) {
        int ra = wm * 64 + i * 16 + l16;
        af[i] = *(const bf16x8*)&lsA[cur][ra * 64 +
                                          (((ks * 4 + quad) ^ (l16 & 7)) * 8)];
        int rb = wn * 64 + i * 16 + l16;
        bfr[i] = *(const bf16x8*)&lsB[cur][rb * 64 +
                                           (((ks * 4 + quad) ^ (l16 & 7)) * 8)];
      }
#pragma unroll
      for (int mi = 0; mi < 4; ++mi)
#pragma unroll
        for (int ni = 0; ni < 4; ++ni)
          acc[mi][ni] = MFMA16(af[mi], bfr[ni], acc[mi][ni]);
    }

    __syncthreads();  // drains prefetch; frees buf[cur] for next overwrite
  }

  if (blockIdx.z == 2 && vtOut != nullptr) {
    // V: write transposed per head -> vt[(b*16+h)][d][s], s contiguous in r
#pragma unroll
    for (int mi = 0; mi < 4; ++mi)
#pragma unroll
      for (int ni = 0; ni < 4; ++ni) {
        int col = n0 + wn * 64 + ni * 16 + l16;       // 0..1023
        int h = col >> 6, d = col & 63;
        int row = m0 + wm * 64 + mi * 16 + quad * 4;  // base of 4 rows
        int b = row >> 11, s = row & 2047;
        bf16 o[4];
#pragma unroll
        for (int r = 0; r < 4; ++r) o[r] = (bf16)acc[mi][ni][r];
        *(ulong1*)&vtOut[((size_t)(b * 16 + h) * 64 + d) * 2048 + s] =
            *(ulong1*)o;
      }
  } else {
#pragma unroll
    for (int mi = 0; mi < 4; ++mi)
#pragma unroll
      for (int ni = 0; ni < 4; ++ni) {
        int col = n0 + wn * 64 + ni * 16 + l16;
#pragma unroll
        for (int r = 0; r < 4; ++r) {
          int row = m0 + wm * 64 + mi * 16 + quad * 4 + r;
          Cz[(size_t)row * 1024 + col] = (OutT)(acc[mi][ni][r] * sc);
        }
      }
  }
}

// ---------------------------------------------------------------------------
// Flash attention: 512 threads, 128-row q-tile, 8 waves x 16 q-rows sharing
// each staged 64-key K/V tile. Fixed-max softmax (Q pre-scaled by
// 0.125*log2e -> p = exp2(s)). K/V double-buffered global_load_lds, one
// barrier per tile. Wave w's diagonal tile ktd = 2qt + (w>>2).
// grid 512: qt = b ? 15-x : x (co-resident pair -> uniform 34 tiles).
// ---------------------------------------------------------------------------
__global__ __launch_bounds__(512, 4) void attn_fwd(
    const bf16* __restrict__ Q, const bf16* __restrict__ K,
    const bf16* __restrict__ Vt, bf16* __restrict__ O) {
  const int bid = blockIdx.x;
  const int x = bid & 15, hb = bid >> 4;
  const int h = hb & 15, b = hb >> 4;
  const int qt = b ? (15 - x) : x;
  const int tid = threadIdx.x;
  const int wave = tid >> 6, lane = tid & 63;
  const int quad = lane >> 4, l16 = lane & 15;

  __shared__ __align__(16) bf16 QsPs[128 * 64];  // Q then Ps, swizzled, 16KB
  __shared__ __align__(16) bf16 Ks[2][64 * 64];  // dbuf, swizzled, 16KB
  __shared__ __align__(16) bf16 Vs[2][64 * 64];  // dbuf, swizzled, [d][s]

  const size_t base = ((size_t)b * 2048) * 1024 + (size_t)h * 64;
  const bf16* Qb = Q + base;
  const bf16* Kb = K + base;
  const bf16* Vtb = Vt + ((size_t)(b * 16 + h)) * 64 * 2048;
  bf16* Ob = O + base;

  const int lrow = lane >> 3;          // 0..7
  const int cgX = (lane & 7) ^ lrow;   // swizzled col-group

  // stage Q (128x64, pre-scaled by 0.125*log2e in QKV GEMM) + K/V tile 0
#pragma unroll
  for (int c = 0; c < 2; ++c) {
    int chunk = wave * 2 + c;  // 16 chunks x 8 rows
    int row = chunk * 8 + lrow;
    async16(&Qb[(size_t)(qt * 128 + row) * 1024 + cgX * 8],
            &QsPs[chunk * 512]);
  }
  {
    int row = wave * 8 + lrow;  // 8 chunks x 8 rows, one per wave
    async16(&Kb[(size_t)row * 1024 + cgX * 8], &Ks[0][wave * 512]);
    async16(&Vtb[(size_t)row * 2048 + cgX * 8], &Vs[0][wave * 512]);
  }
  __syncthreads();

  bf16x8 aq[2];
#pragma unroll
  for (int ks = 0; ks < 2; ++ks) {
    int row = wave * 16 + l16;
    aq[ks] =
        *(const bf16x8*)&QsPs[row * 64 + (((ks * 4 + quad) ^ (l16 & 7)) * 8)];
  }

  const float NEG_INF = -__builtin_inff();
  float ls_acc[4] = {0.f, 0.f, 0.f, 0.f};
  f32x4 Oacc[4];
#pragma unroll
  for (int nt = 0; nt < 4; ++nt) Oacc[nt] = (f32x4){0.f, 0.f, 0.f, 0.f};

  bf16* Psp = &QsPs[0];  // swizzled [128][64] overlay (Q frags in registers)
  const int kt_end = 2 * qt + 1;
  const int ktd = 2 * qt + (wave >> 2);  // this wave's diagonal tile

  for (int kt = 0; kt <= kt_end; ++kt) {
    const int cur = kt & 1;
    if (kt < kt_end) {  // prefetch next K/V tile into alternate buffer
      int row = wave * 8 + lrow;
      async16(&Kb[(size_t)((kt + 1) * 64 + row) * 1024 + cgX * 8],
              &Ks[cur ^ 1][wave * 512]);
      async16(&Vtb[(size_t)row * 2048 + (kt + 1) * 64 + cgX * 8],
              &Vs[cur ^ 1][wave * 512]);
    }

    if (kt <= ktd) {
      // S = Q K^T : 16 q-rows x 64 k-cols for this wave
      f32x4 sv[4];
#pragma unroll
      for (int nt = 0; nt < 4; ++nt) {
        int row = nt * 16 + l16;
        bf16x8 bk0 =
            *(const bf16x8*)&Ks[cur][row * 64 + ((quad ^ (l16 & 7)) * 8)];
        bf16x8 bk1 = *(const bf16x8*)&Ks[cur][row * 64 +
                                             (((4 + quad) ^ (l16 & 7)) * 8)];
        sv[nt] = (f32x4){0.f, 0.f, 0.f, 0.f};
        sv[nt] = MFMA16(aq[0], bk0, sv[nt]);
        sv[nt] = MFMA16(aq[1], bk1, sv[nt]);
      }

      if (kt == ktd) {  // causal mask on this wave's diagonal tile
        const int rowb = wave * 16 + quad * 4;        // row_rel base
        const int cb = (kt - 2 * qt) * 64;            // col_rel base
#pragma unroll
        for (int nt = 0; nt < 4; ++nt) {
          const int col = cb + nt * 16 + l16;
#pragma unroll
          for (int r = 0; r < 4; ++r)
            if (col > rowb + r) sv[nt][r] = NEG_INF;
        }
      }
#pragma unroll
      for (int nt = 0; nt < 4; ++nt)
#pragma unroll
        for (int r = 0; r < 4; ++r) {
          float p = exp2f(sv[nt][r]);
          sv[nt][r] = p;
          ls_acc[r] += p;
        }

      // P: C/D-layout -> A-layout via swizzled LDS (wave-private rows)
#pragma unroll
      for (int nt = 0; nt < 4; ++nt) {
        const int col = nt * 16 + l16;
        const int cg = col >> 3;
#pragma unroll
        for (int r = 0; r < 4; ++r) {
          int prow = wave * 16 + quad * 4 + r;
          Psp[prow * 64 + ((cg ^ (prow & 7)) * 8) + (col & 7)] =
              (bf16)sv[nt][r];
        }
      }

      const int arow = wave * 16 + l16;
      bf16x8 ap0 = *(const bf16x8*)&Psp[arow * 64 + ((quad ^ (l16 & 7)) * 8)];
      bf16x8 ap1 =
          *(const bf16x8*)&Psp[arow * 64 + (((4 + quad) ^ (l16 & 7)) * 8)];
#pragma unroll
      for (int nt = 0; nt < 4; ++nt) {
        int row = nt * 16 + l16;
        bf16x8 bv0 =
            *(const bf16x8*)&Vs[cur][row * 64 + ((quad ^ (l16 & 7)) * 8)];
        bf16x8 bv1 = *(const bf16x8*)&Vs[cur][row * 64 +
                                             (((4 + quad) ^ (l16 & 7)) * 8)];
        Oacc[nt] = MFMA16(ap0, bv0, Oacc[nt]);
        Oacc[nt] = MFMA16(ap1, bv1, Oacc[nt]);
      }
    }

    __syncthreads();  // drains prefetch; publishes buffers
  }

  // epilogue: one DPP reduction for l, normalize, store
  float rl[4];
#pragma unroll
  for (int r = 0; r < 4; ++r) rl[r] = 1.f / rowsum16(ls_acc[r]);
#pragma unroll
  for (int nt = 0; nt < 4; ++nt)
#pragma unroll
    for (int r = 0; r < 4; ++r) {
      int row = qt * 128 + wave * 16 + quad * 4 + r;
      Ob[(size_t)row * 1024 + nt * 16 + l16] = (bf16)(Oacc[nt][r] * rl[r]);
    }
}

// ---------------------------------------------------------------------------
// Launch
// ---------------------------------------------------------------------------
extern "C" void kernel_launch(void* const* d_in, const int* in_sizes, int n_in,
                              void* d_out, int out_size, void* d_ws,
                              size_t ws_size, hipStream_t stream) {
  (void)in_sizes; (void)n_in; (void)out_size; (void)ws_size;
  const float* x  = (const float*)d_in[0];
  const float* Wq = (const float*)d_in[1];
  const float* Wk = (const float*)d_in[2];
  const float* Wv = (const float*)d_in[3];
  const float* Wo = (const float*)d_in[4];
  float* out = (float*)d_out;

  bf16* ws = (bf16*)d_ws;
  const size_t WELEM = 1024u * 1024u;
  const size_t TELEM = 4096u * 1024u;
  bf16* wt  = ws;               // 4 transposed weights (8 MB)
  bf16* xbf = ws + 4 * WELEM;   // x bf16 (8 MB)
  bf16* q   = xbf + TELEM;      // q (z=0), k (z=1) via cStrideZ
  bf16* k   = q + TELEM;
  bf16* vt  = k + TELEM;        // V written pre-transposed by QKV epilogue
  bf16* ao  = vt + TELEM;

  const float QSCALE = 0.125f * 1.44269504088896340736f;  // 1/sqrt(64)*log2e

  convert_x<<<dim3(4096), 256, 0, stream>>>(x, xbf);
  transpose_w<<<dim3(16, 16, 4), 256, 0, stream>>>(Wq, Wk, Wv, Wo, wt);
  gemm_bt<bf16><<<dim3(8, 32, 3), 256, 0, stream>>>(xbf, wt, q, (int)WELEM,
                                                    (int)TELEM, QSCALE, vt);
  attn_fwd<<<dim3(512), 512, 0, stream>>>(q, k, vt, ao);
  gemm_bt<float><<<dim3(8, 32, 1), 256, 0, stream>>>(ao, wt + 3 * WELEM, out,
                                                     0, 0, 1.0f, nullptr);
}

// Round 11
// 198.331 us; speedup vs baseline: 1.0583x; 1.0583x over previous
//
#include <hip/hip_runtime.h>
#include <hip/hip_bf16.h>

typedef __bf16 bf16;
typedef __bf16 bf16x8 __attribute__((ext_vector_type(8)));
typedef float f32x4 __attribute__((ext_vector_type(4)));

#define MFMA16(a, b, c) __builtin_amdgcn_mfma_f32_16x16x32_bf16((a), (b), (c), 0, 0, 0)

// async global->LDS, 16B per lane; LDS dest = wave-uniform base + lane*16.
__device__ __forceinline__ void async16(const void* g, void* l) {
  typedef const unsigned int __attribute__((address_space(1))) * GP;
  typedef unsigned int __attribute__((address_space(3))) * LP;
  __builtin_amdgcn_global_load_lds((GP)g, (LP)l, 16, 0, 0);
}

// ---- DPP 16-lane row sum (epilogue only) -----------------------------------
template <int ctrl>
__device__ __forceinline__ float dppf(float v) {
  return __builtin_bit_cast(
      float, __builtin_amdgcn_update_dpp(0, __builtin_bit_cast(int, v), ctrl,
                                         0xf, 0xf, true));
}
__device__ __forceinline__ float rowsum16(float x) {
  x += dppf<0xB1>(x);
  x += dppf<0x4E>(x);
  x += dppf<0x141>(x);
  x += dppf<0x140>(x);
  return x;
}

// ---------------------------------------------------------------------------
// Convert x: fp32 [4M] -> bf16 [4M].
// ---------------------------------------------------------------------------
__global__ __launch_bounds__(256) void convert_x(
    const float* __restrict__ src, bf16* __restrict__ dst) {
  int i = (blockIdx.x * 256 + threadIdx.x) * 4;
  f32x4 v = *(const f32x4*)&src[i];
  bf16 o[4];
#pragma unroll
  for (int j = 0; j < 4; ++j) o[j] = (bf16)v[j];
  *(ulong1*)&dst[i] = *(ulong1*)o;
}

// ---------------------------------------------------------------------------
// Transpose+convert 4 weight matrices fp32 [1024x1024] -> bf16 Wt[n][k].
// ---------------------------------------------------------------------------
__global__ __launch_bounds__(256) void transpose_w(
    const float* __restrict__ w0, const float* __restrict__ w1,
    const float* __restrict__ w2, const float* __restrict__ w3,
    bf16* __restrict__ out) {
  __shared__ __align__(16) float tile[64][68];
  const float* src = (blockIdx.z == 0) ? w0 : (blockIdx.z == 1) ? w1
                   : (blockIdx.z == 2) ? w2 : w3;
  bf16* dst = out + (size_t)blockIdx.z * (1024u * 1024u);
  const int t = threadIdx.x;
  const int bx = blockIdx.x, by = blockIdx.y;

#pragma unroll
  for (int p = 0; p < 4; ++p) {
    int idx = t + p * 256;
    int r = idx >> 4, c4 = idx & 15;
    *(f32x4*)&tile[r][c4 * 4] =
        *(const f32x4*)&src[(size_t)(by * 64 + r) * 1024 + bx * 64 + c4 * 4];
  }
  __syncthreads();
#pragma unroll
  for (int p = 0; p < 2; ++p) {
    int idx = t + p * 256;
    int rn = idx >> 3, c8 = idx & 7;
    bf16x8 v;
#pragma unroll
    for (int i = 0; i < 8; ++i) v[i] = (bf16)tile[c8 * 8 + i][rn];
    *(bf16x8*)&dst[(size_t)(bx * 64 + rn) * 1024 + by * 64 + c8 * 8] = v;
  }
}

// ---------------------------------------------------------------------------
// GEMM: C[M x 1024] = A[M x 1024] @ W (Bt[n][k]). Block tile 128 x (NI*32).
// BK=32, double-buffered global_load_lds staging, ONE barrier per K-step
// (round-9 structure: prefetch k+1 into alt buffer, compute k, barrier).
// Swizzle: lds[row][cg ^ ((row>>1)&3)] -> frag reads 2-way aliased (free).
// z==0 scaled by scaleZ0 (folds softmax 1/8*log2e into Q).
// z==2 with vtOut: write transposed per head into vt[bh][d][s] (fused V^T).
// grid: (1024/(NI*32), M/128, nz). NI=2 -> 24KB LDS, 4-5 blocks/CU.
// ---------------------------------------------------------------------------
template <typename OutT, int NI>
__global__ __launch_bounds__(256, 4) void gemm_bt(
    const bf16* __restrict__ A, const bf16* __restrict__ Bt,
    OutT* __restrict__ C, int btStrideZ, int cStrideZ, float scaleZ0,
    bf16* __restrict__ vtOut) {
  const int tid = threadIdx.x;
  const int wave = tid >> 6, lane = tid & 63;
  const int quad = lane >> 4, l16 = lane & 15;
  const int wm = wave >> 1, wn = wave & 1;
  const int m0 = blockIdx.y * 128, n0 = blockIdx.x * (NI * 32);
  const bf16* Bz = Bt + (size_t)blockIdx.z * (size_t)btStrideZ;
  OutT* Cz = C + (size_t)blockIdx.z * (size_t)cStrideZ;
  const float sc = (blockIdx.z == 0) ? scaleZ0 : 1.0f;

  __shared__ __align__(16) bf16 lsA[2][128 * 32];       // 8KB per buf
  __shared__ __align__(16) bf16 lsB[2][NI * 32 * 32];   // NI*2KB per buf

  const int lrow = lane >> 2;                      // 0..15 in 16-row chunk
  const int cgX = (lane & 3) ^ ((lrow >> 1) & 3);  // swizzled col-group
  const int fR = (l16 >> 1) & 3;                   // read-side swizzle term

  f32x4 acc[4][NI];
#pragma unroll
  for (int i = 0; i < 4; ++i)
#pragma unroll
    for (int j = 0; j < NI; ++j) acc[i][j] = (f32x4){0.f, 0.f, 0.f, 0.f};

  // preload K-step 0 into buffer 0
#pragma unroll
  for (int c = 0; c < 2; ++c) {
    int chunk = wave * 2 + c;  // A: 8 chunks x 16 rows
    int row = chunk * 16 + lrow;
    async16(&A[(size_t)(m0 + row) * 1024 + cgX * 8], &lsA[0][chunk * 512]);
  }
#pragma unroll
  for (int c = 0; c < NI / 2; ++c) {
    int chunk = wave * (NI / 2) + c;  // B: NI*2 chunks x 16 rows
    int row = chunk * 16 + lrow;
    async16(&Bz[(size_t)(n0 + row) * 1024 + cgX * 8], &lsB[0][chunk * 512]);
  }
  __syncthreads();

  for (int it = 0; it < 32; ++it) {
    const int cur = it & 1;
    if (it < 31) {  // prefetch next K-step into the alternate buffer
      int k0n = (it + 1) * 32;
#pragma unroll
      for (int c = 0; c < 2; ++c) {
        int chunk = wave * 2 + c;
        int row = chunk * 16 + lrow;
        async16(&A[(size_t)(m0 + row) * 1024 + k0n + cgX * 8],
                &lsA[cur ^ 1][chunk * 512]);
      }
#pragma unroll
      for (int c = 0; c < NI / 2; ++c) {
        int chunk = wave * (NI / 2) + c;
        int row = chunk * 16 + lrow;
        async16(&Bz[(size_t)(n0 + row) * 1024 + k0n + cgX * 8],
                &lsB[cur ^ 1][chunk * 512]);
      }
    }

    bf16x8 af[4], bfr[NI];
#pragma unroll
    for (int i = 0; i < 4; ++i) {
      int ra = wm * 64 + i * 16 + l16;
      af[i] = *(const bf16x8*)&lsA[cur][ra * 32 + ((quad ^ fR) * 8)];
    }
#pragma unroll
    for (int ni = 0; ni < NI; ++ni) {
      int rb = wn * (NI * 16) + ni * 16 + l16;
      bfr[ni] = *(const bf16x8*)&lsB[cur][rb * 32 + ((quad ^ fR) * 8)];
    }
#pragma unroll
    for (int mi = 0; mi < 4; ++mi)
#pragma unroll
      for (int ni = 0; ni < NI; ++ni)
        acc[mi][ni] = MFMA16(af[mi], bfr[ni], acc[mi][ni]);

    __syncthreads();  // drains prefetch; frees buf[cur] for next overwrite
  }

  if (blockIdx.z == 2 && vtOut != nullptr) {
    // V: write transposed per head -> vt[(b*16+h)][d][s], s contiguous in r
#pragma unroll
    for (int mi = 0; mi < 4; ++mi)
#pragma unroll
      for (int ni = 0; ni < NI; ++ni) {
        int col = n0 + wn * (NI * 16) + ni * 16 + l16;  // 0..1023
        int h = col >> 6, d = col & 63;
        int row = m0 + wm * 64 + mi * 16 + quad * 4;    // base of 4 rows
        int b = row >> 11, s = row & 2047;
        bf16 o[4];
#pragma unroll
        for (int r = 0; r < 4; ++r) o[r] = (bf16)acc[mi][ni][r];
        *(ulong1*)&vtOut[((size_t)(b * 16 + h) * 64 + d) * 2048 + s] =
            *(ulong1*)o;
      }
  } else {
#pragma unroll
    for (int mi = 0; mi < 4; ++mi)
#pragma unroll
      for (int ni = 0; ni < NI; ++ni) {
        int col = n0 + wn * (NI * 16) + ni * 16 + l16;
#pragma unroll
        for (int r = 0; r < 4; ++r) {
          int row = m0 + wm * 64 + mi * 16 + quad * 4 + r;
          Cz[(size_t)row * 1024 + col] = (OutT)(acc[mi][ni][r] * sc);
        }
      }
  }
}

// ---------------------------------------------------------------------------
// Flash attention (round-9 version, unchanged): 512 threads, 128-row q-tile,
// 8 waves x 16 q-rows sharing each staged 64-key K/V tile. Fixed-max softmax
// (Q pre-scaled by 0.125*log2e -> p = exp2(s)). K/V double-buffered
// global_load_lds, one barrier per tile. ktd = 2qt + (wave>>2).
// grid 512: qt = b ? 15-x : x (uniform 34 tiles per co-resident pair).
// ---------------------------------------------------------------------------
__global__ __launch_bounds__(512, 4) void attn_fwd(
    const bf16* __restrict__ Q, const bf16* __restrict__ K,
    const bf16* __restrict__ Vt, bf16* __restrict__ O) {
  const int bid = blockIdx.x;
  const int x = bid & 15, hb = bid >> 4;
  const int h = hb & 15, b = hb >> 4;
  const int qt = b ? (15 - x) : x;
  const int tid = threadIdx.x;
  const int wave = tid >> 6, lane = tid & 63;
  const int quad = lane >> 4, l16 = lane & 15;

  __shared__ __align__(16) bf16 QsPs[128 * 64];  // Q then Ps, swizzled, 16KB
  __shared__ __align__(16) bf16 Ks[2][64 * 64];  // dbuf, swizzled, 16KB
  __shared__ __align__(16) bf16 Vs[2][64 * 64];  // dbuf, swizzled, [d][s]

  const size_t base = ((size_t)b * 2048) * 1024 + (size_t)h * 64;
  const bf16* Qb = Q + base;
  const bf16* Kb = K + base;
  const bf16* Vtb = Vt + ((size_t)(b * 16 + h)) * 64 * 2048;
  bf16* Ob = O + base;

  const int lrow = lane >> 3;          // 0..7
  const int cgX = (lane & 7) ^ lrow;   // swizzled col-group

  // stage Q (128x64, pre-scaled by 0.125*log2e in QKV GEMM) + K/V tile 0
#pragma unroll
  for (int c = 0; c < 2; ++c) {
    int chunk = wave * 2 + c;  // 16 chunks x 8 rows
    int row = chunk * 8 + lrow;
    async16(&Qb[(size_t)(qt * 128 + row) * 1024 + cgX * 8],
            &QsPs[chunk * 512]);
  }
  {
    int row = wave * 8 + lrow;  // 8 chunks x 8 rows, one per wave
    async16(&Kb[(size_t)row * 1024 + cgX * 8], &Ks[0][wave * 512]);
    async16(&Vtb[(size_t)row * 2048 + cgX * 8], &Vs[0][wave * 512]);
  }
  __syncthreads();

  bf16x8 aq[2];
#pragma unroll
  for (int ks = 0; ks < 2; ++ks) {
    int row = wave * 16 + l16;
    aq[ks] =
        *(const bf16x8*)&QsPs[row * 64 + (((ks * 4 + quad) ^ (l16 & 7)) * 8)];
  }

  const float NEG_INF = -__builtin_inff();
  float ls_acc[4] = {0.f, 0.f, 0.f, 0.f};
  f32x4 Oacc[4];
#pragma unroll
  for (int nt = 0; nt < 4; ++nt) Oacc[nt] = (f32x4){0.f, 0.f, 0.f, 0.f};

  bf16* Psp = &QsPs[0];  // swizzled [128][64] overlay (Q frags in registers)
  const int kt_end = 2 * qt + 1;
  const int ktd = 2 * qt + (wave >> 2);  // this wave's diagonal tile

  for (int kt = 0; kt <= kt_end; ++kt) {
    const int cur = kt & 1;
    if (kt < kt_end) {  // prefetch next K/V tile into alternate buffer
      int row = wave * 8 + lrow;
      async16(&Kb[(size_t)((kt + 1) * 64 + row) * 1024 + cgX * 8],
              &Ks[cur ^ 1][wave * 512]);
      async16(&Vtb[(size_t)row * 2048 + (kt + 1) * 64 + cgX * 8],
              &Vs[cur ^ 1][wave * 512]);
    }

    if (kt <= ktd) {
      // S = Q K^T : 16 q-rows x 64 k-cols for this wave
      f32x4 sv[4];
#pragma unroll
      for (int nt = 0; nt < 4; ++nt) {
        int row = nt * 16 + l16;
        bf16x8 bk0 =
            *(const bf16x8*)&Ks[cur][row * 64 + ((quad ^ (l16 & 7)) * 8)];
        bf16x8 bk1 = *(const bf16x8*)&Ks[cur][row * 64 +
                                             (((4 + quad) ^ (l16 & 7)) * 8)];
        sv[nt] = (f32x4){0.f, 0.f, 0.f, 0.f};
        sv[nt] = MFMA16(aq[0], bk0, sv[nt]);
        sv[nt] = MFMA16(aq[1], bk1, sv[nt]);
      }

      if (kt == ktd) {  // causal mask on this wave's diagonal tile
        const int rowb = wave * 16 + quad * 4;        // row_rel base
        const int cb = (kt - 2 * qt) * 64;            // col_rel base
#pragma unroll
        for (int nt = 0; nt < 4; ++nt) {
          const int col = cb + nt * 16 + l16;
#pragma unroll
          for (int r = 0; r < 4; ++r)
            if (col > rowb + r) sv[nt][r] = NEG_INF;
        }
      }
#pragma unroll
      for (int nt = 0; nt < 4; ++nt)
#pragma unroll
        for (int r = 0; r < 4; ++r) {
          float p = exp2f(sv[nt][r]);
          sv[nt][r] = p;
          ls_acc[r] += p;
        }

      // P: C/D-layout -> A-layout via swizzled LDS (wave-private rows)
#pragma unroll
      for (int nt = 0; nt < 4; ++nt) {
        const int col = nt * 16 + l16;
        const int cg = col >> 3;
#pragma unroll
        for (int r = 0; r < 4; ++r) {
          int prow = wave * 16 + quad * 4 + r;
          Psp[prow * 64 + ((cg ^ (prow & 7)) * 8) + (col & 7)] =
              (bf16)sv[nt][r];
        }
      }

      const int arow = wave * 16 + l16;
      bf16x8 ap0 = *(const bf16x8*)&Psp[arow * 64 + ((quad ^ (l16 & 7)) * 8)];
      bf16x8 ap1 =
          *(const bf16x8*)&Psp[arow * 64 + (((4 + quad) ^ (l16 & 7)) * 8)];
#pragma unroll
      for (int nt = 0; nt < 4; ++nt) {
        int row = nt * 16 + l16;
        bf16x8 bv0 =
            *(const bf16x8*)&Vs[cur][row * 64 + ((quad ^ (l16 & 7)) * 8)];
        bf16x8 bv1 = *(const bf16x8*)&Vs[cur][row * 64 +
                                             (((4 + quad) ^ (l16 & 7)) * 8)];
        Oacc[nt] = MFMA16(ap0, bv0, Oacc[nt]);
        Oacc[nt] = MFMA16(ap1, bv1, Oacc[nt]);
      }
    }

    __syncthreads();  // drains prefetch; publishes buffers
  }

  // epilogue: one DPP reduction for l, normalize, store
  float rl[4];
#pragma unroll
  for (int r = 0; r < 4; ++r) rl[r] = 1.f / rowsum16(ls_acc[r]);
#pragma unroll
  for (int nt = 0; nt < 4; ++nt)
#pragma unroll
    for (int r = 0; r < 4; ++r) {
      int row = qt * 128 + wave * 16 + quad * 4 + r;
      Ob[(size_t)row * 1024 + nt * 16 + l16] = (bf16)(Oacc[nt][r] * rl[r]);
    }
}

// ---------------------------------------------------------------------------
// Launch
// ---------------------------------------------------------------------------
extern "C" void kernel_launch(void* const* d_in, const int* in_sizes, int n_in,
                              void* d_out, int out_size, void* d_ws,
                              size_t ws_size, hipStream_t stream) {
  (void)in_sizes; (void)n_in; (void)out_size; (void)ws_size;
  const float* x  = (const float*)d_in[0];
  const float* Wq = (const float*)d_in[1];
  const float* Wk = (const float*)d_in[2];
  const float* Wv = (const float*)d_in[3];
  const float* Wo = (const float*)d_in[4];
  float* out = (float*)d_out;

  bf16* ws = (bf16*)d_ws;
  const size_t WELEM = 1024u * 1024u;
  const size_t TELEM = 4096u * 1024u;
  bf16* wt  = ws;               // 4 transposed weights (8 MB)
  bf16* xbf = ws + 4 * WELEM;   // x bf16 (8 MB)
  bf16* q   = xbf + TELEM;      // q (z=0), k (z=1) via cStrideZ
  bf16* k   = q + TELEM;
  bf16* vt  = k + TELEM;        // V written pre-transposed by QKV epilogue
  bf16* ao  = vt + TELEM;

  const float QSCALE = 0.125f * 1.44269504088896340736f;  // 1/sqrt(64)*log2e

  convert_x<<<dim3(4096), 256, 0, stream>>>(x, xbf);
  transpose_w<<<dim3(16, 16, 4), 256, 0, stream>>>(Wq, Wk, Wv, Wo, wt);
  gemm_bt<bf16, 2><<<dim3(16, 32, 3), 256, 0, stream>>>(
      xbf, wt, q, (int)WELEM, (int)TELEM, QSCALE, vt);
  attn_fwd<<<dim3(512), 512, 0, stream>>>(q, k, vt, ao);
  gemm_bt<float, 2><<<dim3(16, 32, 1), 256, 0, stream>>>(
      ao, wt + 3 * WELEM, out, 0, 0, 1.0f, nullptr);
}

// Round 12
// 190.592 us; speedup vs baseline: 1.1013x; 1.0406x over previous
//
#include <hip/hip_runtime.h>
#include <hip/hip_bf16.h>

typedef __bf16 bf16;
typedef __bf16 bf16x4 __attribute__((ext_vector_type(4)));
typedef __bf16 bf16x8 __attribute__((ext_vector_type(8)));
typedef float f32x4 __attribute__((ext_vector_type(4)));

#define MFMA16(a, b, c) __builtin_amdgcn_mfma_f32_16x16x32_bf16((a), (b), (c), 0, 0, 0)

// async global->LDS, 16B per lane; LDS dest = wave-uniform base + lane*16.
__device__ __forceinline__ void async16(const void* g, void* l) {
  typedef const unsigned int __attribute__((address_space(1))) * GP;
  typedef unsigned int __attribute__((address_space(3))) * LP;
  __builtin_amdgcn_global_load_lds((GP)g, (LP)l, 16, 0, 0);
}

// ---------------------------------------------------------------------------
// prep: z<4 -> transpose+convert weight z (fp32 [1024x1024] -> bf16 Wt[n][k]);
// z==4 -> convert x fp32 -> bf16 (256 chunks of 16384 elems).
// grid (16,16,5) x 256 threads.
// ---------------------------------------------------------------------------
__global__ __launch_bounds__(256) void prep(
    const float* __restrict__ w0, const float* __restrict__ w1,
    const float* __restrict__ w2, const float* __restrict__ w3,
    const float* __restrict__ x, bf16* __restrict__ wtOut,
    bf16* __restrict__ xOut) {
  const int t = threadIdx.x;
  if (blockIdx.z == 4) {  // x conversion
    size_t base = ((size_t)(blockIdx.y * 16 + blockIdx.x)) * 16384;
#pragma unroll
    for (int p = 0; p < 16; ++p) {
      size_t i = base + (size_t)(p * 256 + t) * 4;
      f32x4 v = *(const f32x4*)&x[i];
      bf16 o[4];
#pragma unroll
      for (int j = 0; j < 4; ++j) o[j] = (bf16)v[j];
      *(ulong1*)&xOut[i] = *(ulong1*)o;
    }
    return;
  }
  __shared__ __align__(16) float tile[64][68];
  const float* src = (blockIdx.z == 0) ? w0 : (blockIdx.z == 1) ? w1
                   : (blockIdx.z == 2) ? w2 : w3;
  bf16* dst = wtOut + (size_t)blockIdx.z * (1024u * 1024u);
  const int bx = blockIdx.x, by = blockIdx.y;
#pragma unroll
  for (int p = 0; p < 4; ++p) {
    int idx = t + p * 256;
    int r = idx >> 4, c4 = idx & 15;
    *(f32x4*)&tile[r][c4 * 4] =
        *(const f32x4*)&src[(size_t)(by * 64 + r) * 1024 + bx * 64 + c4 * 4];
  }
  __syncthreads();
#pragma unroll
  for (int p = 0; p < 2; ++p) {
    int idx = t + p * 256;
    int rn = idx >> 3, c8 = idx & 7;
    bf16x8 v;
#pragma unroll
    for (int i = 0; i < 8; ++i) v[i] = (bf16)tile[c8 * 8 + i][rn];
    *(bf16x8*)&dst[(size_t)(bx * 64 + rn) * 1024 + by * 64 + c8 * 8] = v;
  }
}

// ---------------------------------------------------------------------------
// GEMM (round-11): C[M x 1024] = A @ W (Bt[n][k]). 128 x (NI*32) tile, BK=32
// double-buffered global_load_lds, one barrier per K-step.
// z==0 scaled by scaleZ0; z==2 with vtOut: fused V^T epilogue.
// ---------------------------------------------------------------------------
template <typename OutT, int NI>
__global__ __launch_bounds__(256, 4) void gemm_bt(
    const bf16* __restrict__ A, const bf16* __restrict__ Bt,
    OutT* __restrict__ C, int btStrideZ, int cStrideZ, float scaleZ0,
    bf16* __restrict__ vtOut) {
  const int tid = threadIdx.x;
  const int wave = tid >> 6, lane = tid & 63;
  const int quad = lane >> 4, l16 = lane & 15;
  const int wm = wave >> 1, wn = wave & 1;
  const int m0 = blockIdx.y * 128, n0 = blockIdx.x * (NI * 32);
  const bf16* Bz = Bt + (size_t)blockIdx.z * (size_t)btStrideZ;
  OutT* Cz = C + (size_t)blockIdx.z * (size_t)cStrideZ;
  const float sc = (blockIdx.z == 0) ? scaleZ0 : 1.0f;

  __shared__ __align__(16) bf16 lsA[2][128 * 32];
  __shared__ __align__(16) bf16 lsB[2][NI * 32 * 32];

  const int lrow = lane >> 2;
  const int cgX = (lane & 3) ^ ((lrow >> 1) & 3);
  const int fR = (l16 >> 1) & 3;

  f32x4 acc[4][NI];
#pragma unroll
  for (int i = 0; i < 4; ++i)
#pragma unroll
    for (int j = 0; j < NI; ++j) acc[i][j] = (f32x4){0.f, 0.f, 0.f, 0.f};

#pragma unroll
  for (int c = 0; c < 2; ++c) {
    int chunk = wave * 2 + c;
    int row = chunk * 16 + lrow;
    async16(&A[(size_t)(m0 + row) * 1024 + cgX * 8], &lsA[0][chunk * 512]);
  }
#pragma unroll
  for (int c = 0; c < NI / 2; ++c) {
    int chunk = wave * (NI / 2) + c;
    int row = chunk * 16 + lrow;
    async16(&Bz[(size_t)(n0 + row) * 1024 + cgX * 8], &lsB[0][chunk * 512]);
  }
  __syncthreads();

  for (int it = 0; it < 32; ++it) {
    const int cur = it & 1;
    if (it < 31) {
      int k0n = (it + 1) * 32;
#pragma unroll
      for (int c = 0; c < 2; ++c) {
        int chunk = wave * 2 + c;
        int row = chunk * 16 + lrow;
        async16(&A[(size_t)(m0 + row) * 1024 + k0n + cgX * 8],
                &lsA[cur ^ 1][chunk * 512]);
      }
#pragma unroll
      for (int c = 0; c < NI / 2; ++c) {
        int chunk = wave * (NI / 2) + c;
        int row = chunk * 16 + lrow;
        async16(&Bz[(size_t)(n0 + row) * 1024 + k0n + cgX * 8],
                &lsB[cur ^ 1][chunk * 512]);
      }
    }

    bf16x8 af[4], bfr[NI];
#pragma unroll
    for (int i = 0; i < 4; ++i) {
      int ra = wm * 64 + i * 16 + l16;
      af[i] = *(const bf16x8*)&lsA[cur][ra * 32 + ((quad ^ fR) * 8)];
    }
#pragma unroll
    for (int ni = 0; ni < NI; ++ni) {
      int rb = wn * (NI * 16) + ni * 16 + l16;
      bfr[ni] = *(const bf16x8*)&lsB[cur][rb * 32 + ((quad ^ fR) * 8)];
    }
#pragma unroll
    for (int mi = 0; mi < 4; ++mi)
#pragma unroll
      for (int ni = 0; ni < NI; ++ni)
        acc[mi][ni] = MFMA16(af[mi], bfr[ni], acc[mi][ni]);

    __syncthreads();
  }

  if (blockIdx.z == 2 && vtOut != nullptr) {
#pragma unroll
    for (int mi = 0; mi < 4; ++mi)
#pragma unroll
      for (int ni = 0; ni < NI; ++ni) {
        int col = n0 + wn * (NI * 16) + ni * 16 + l16;
        int h = col >> 6, d = col & 63;
        int row = m0 + wm * 64 + mi * 16 + quad * 4;
        int b = row >> 11, s = row & 2047;
        bf16 o[4];
#pragma unroll
        for (int r = 0; r < 4; ++r) o[r] = (bf16)acc[mi][ni][r];
        *(ulong1*)&vtOut[((size_t)(b * 16 + h) * 64 + d) * 2048 + s] =
            *(ulong1*)o;
      }
  } else {
#pragma unroll
    for (int mi = 0; mi < 4; ++mi)
#pragma unroll
      for (int ni = 0; ni < NI; ++ni) {
        int col = n0 + wn * (NI * 16) + ni * 16 + l16;
#pragma unroll
        for (int r = 0; r < 4; ++r) {
          int row = m0 + wm * 64 + mi * 16 + quad * 4 + r;
          Cz[(size_t)row * 1024 + col] = (OutT)(acc[mi][ni][r] * sc);
        }
      }
  }
}

// ---------------------------------------------------------------------------
// Flash attention v4: REGISTER-RESIDENT P.
// S^T = K Q^T (A=K-frag, B=Q-frag -> lane holds (key=nt*16+quad*4+r, q=l16)),
// which IS the A-frag pattern for PV: pack two 16-key groups into one bf16x8
// (slots 0-3 = group 2a, 4-7 = group 2a+1) and feed matching V B-frags (two
// ds_read_b64 from Vs[d][s]) -> PV = 8 full-rate 16x16x32 MFMA, no P LDS
// round-trip. l is per-lane scalar (all keys belong to q=l16); reduced with
// 2 shuffles + 4 shfl in the epilogue only.
// LDS 32KB: K/V dbuf-1 overlays the Q staging region (Q frags hoisted to
// registers behind an extra barrier). 512 thr, 128-row q-tile, grid 512.
// ---------------------------------------------------------------------------
__global__ __launch_bounds__(512, 4) void attn_fwd(
    const bf16* __restrict__ Q, const bf16* __restrict__ K,
    const bf16* __restrict__ Vt, bf16* __restrict__ O) {
  const int bid = blockIdx.x;
  const int x = bid & 15, hb = bid >> 4;
  const int h = hb & 15, b = hb >> 4;
  const int qt = b ? (15 - x) : x;
  const int tid = threadIdx.x;
  const int wave = tid >> 6, lane = tid & 63;
  const int quad = lane >> 4, l16 = lane & 15;

  __shared__ __align__(16) bf16 SMEM[16384];  // 32 KB
  // layout: [0,4096) K0 | [4096,8192) V0 | [8192,12288) K1 | [12288,16384) V1
  // Q staging overlays [8192,16384) (freed after Q-frag hoist).
  const int kof[2] = {0, 8192};
  const int vof[2] = {4096, 12288};
  bf16* Qs = &SMEM[8192];

  const size_t base = ((size_t)b * 2048) * 1024 + (size_t)h * 64;
  const bf16* Qb = Q + base;
  const bf16* Kb = K + base;
  const bf16* Vtb = Vt + ((size_t)(b * 16 + h)) * 64 * 2048;
  bf16* Ob = O + base;

  const int lrow = lane >> 3;          // 0..7
  const int cgX = (lane & 7) ^ lrow;   // swizzled col-group

  // stage Q (128x64, pre-scaled by 0.125*log2e in QKV GEMM) + K/V tile 0
#pragma unroll
  for (int c = 0; c < 2; ++c) {
    int chunk = wave * 2 + c;  // 16 chunks x 8 rows
    int row = chunk * 8 + lrow;
    async16(&Qb[(size_t)(qt * 128 + row) * 1024 + cgX * 8], &Qs[chunk * 512]);
  }
  {
    int row = wave * 8 + lrow;  // 8 chunks x 8 rows, one per wave
    async16(&Kb[(size_t)row * 1024 + cgX * 8], &SMEM[kof[0] + wave * 512]);
    async16(&Vtb[(size_t)row * 2048 + cgX * 8], &SMEM[vof[0] + wave * 512]);
  }
  __syncthreads();

  bf16x8 aq[2];
#pragma unroll
  for (int ks = 0; ks < 2; ++ks) {
    int row = wave * 16 + l16;
    aq[ks] = *(const bf16x8*)&Qs[row * 64 + (((ks * 4 + quad) ^ (l16 & 7)) * 8)];
  }
  __syncthreads();  // all Q-frag reads done before buf1 (Q overlay) is written

  const float NEG_INF = -__builtin_inff();
  float ls_acc = 0.f;
  f32x4 Oacc[4];
#pragma unroll
  for (int nt = 0; nt < 4; ++nt) Oacc[nt] = (f32x4){0.f, 0.f, 0.f, 0.f};

  const int kt_end = 2 * qt + 1;
  const int ktd = 2 * qt + (wave >> 2);  // this wave's diagonal tile

  for (int kt = 0; kt <= kt_end; ++kt) {
    const int cur = kt & 1;
    if (kt < kt_end) {  // prefetch next K/V tile into alternate buffer
      int row = wave * 8 + lrow;
      async16(&Kb[(size_t)((kt + 1) * 64 + row) * 1024 + cgX * 8],
              &SMEM[kof[cur ^ 1] + wave * 512]);
      async16(&Vtb[(size_t)row * 2048 + (kt + 1) * 64 + cgX * 8],
              &SMEM[vof[cur ^ 1] + wave * 512]);
    }

    if (kt <= ktd) {
      // S^T = K Q^T : lane -> (key = nt*16+quad*4+r, q = l16)
      f32x4 sv[4];
#pragma unroll
      for (int nt = 0; nt < 4; ++nt) {
        int row = nt * 16 + l16;  // key row in Ks
        bf16x8 bk0 = *(const bf16x8*)&SMEM[kof[cur] + row * 64 +
                                           ((quad ^ (l16 & 7)) * 8)];
        bf16x8 bk1 = *(const bf16x8*)&SMEM[kof[cur] + row * 64 +
                                           (((4 + quad) ^ (l16 & 7)) * 8)];
        sv[nt] = (f32x4){0.f, 0.f, 0.f, 0.f};
        sv[nt] = MFMA16(bk0, aq[0], sv[nt]);  // A = K-frag, B = Q-frag
        sv[nt] = MFMA16(bk1, aq[1], sv[nt]);
      }

      if (kt == ktd) {  // causal mask: key_rel > q_rel
        const int q_rel = wave * 16 + l16;
        const int cb = (kt - 2 * qt) * 64;
#pragma unroll
        for (int nt = 0; nt < 4; ++nt) {
          const int kb = cb + nt * 16 + quad * 4;
#pragma unroll
          for (int r = 0; r < 4; ++r)
            if (kb + r > q_rel) sv[nt][r] = NEG_INF;
        }
      }

      // exp2 + pack P into A-frags (two 16-key groups per bf16x8)
      bf16x8 apf[2];
#pragma unroll
      for (int a = 0; a < 2; ++a)
#pragma unroll
        for (int g = 0; g < 2; ++g)
#pragma unroll
          for (int r = 0; r < 4; ++r) {
            float p = exp2f(sv[a * 2 + g][r]);
            ls_acc += p;
            apf[a][g * 4 + r] = (bf16)p;
          }

      // PV: D[q][d] += P[q][k] V[k][d], B-frags = two b64 reads from Vs
#pragma unroll
      for (int nt = 0; nt < 4; ++nt) {  // d-group
        const int R = nt * 16 + l16;
        const int sub = (quad & 1) * 4;
#pragma unroll
        for (int a = 0; a < 2; ++a) {
          const int g0 = a * 4 + (quad >> 1);      // col-group of keys j=0..3
          const int g1 = g0 + 2;                   // col-group of keys j=4..7
          bf16x4 lo = *(const bf16x4*)&SMEM[vof[cur] + R * 64 +
                                            ((g0 ^ (l16 & 7)) * 8) + sub];
          bf16x4 hi = *(const bf16x4*)&SMEM[vof[cur] + R * 64 +
                                            ((g1 ^ (l16 & 7)) * 8) + sub];
          bf16x8 bvf;
#pragma unroll
          for (int i = 0; i < 4; ++i) {
            bvf[i] = lo[i];
            bvf[4 + i] = hi[i];
          }
          Oacc[nt] = MFMA16(apf[a], bvf, Oacc[nt]);
        }
      }
    }

    __syncthreads();  // drains prefetch; publishes buffers
  }

  // epilogue: l(q=l16) = sum over quads; redistribute to q=quad*4+r via shfl
  ls_acc += __shfl_xor(ls_acc, 16, 64);
  ls_acc += __shfl_xor(ls_acc, 32, 64);
  float rl[4];
#pragma unroll
  for (int r = 0; r < 4; ++r) rl[r] = 1.f / __shfl(ls_acc, quad * 4 + r, 64);
#pragma unroll
  for (int nt = 0; nt < 4; ++nt)
#pragma unroll
    for (int r = 0; r < 4; ++r) {
      int row = qt * 128 + wave * 16 + quad * 4 + r;
      Ob[(size_t)row * 1024 + nt * 16 + l16] = (bf16)(Oacc[nt][r] * rl[r]);
    }
}

// ---------------------------------------------------------------------------
// Launch
// ---------------------------------------------------------------------------
extern "C" void kernel_launch(void* const* d_in, const int* in_sizes, int n_in,
                              void* d_out, int out_size, void* d_ws,
                              size_t ws_size, hipStream_t stream) {
  (void)in_sizes; (void)n_in; (void)out_size; (void)ws_size;
  const float* x  = (const float*)d_in[0];
  const float* Wq = (const float*)d_in[1];
  const float* Wk = (const float*)d_in[2];
  const float* Wv = (const float*)d_in[3];
  const float* Wo = (const float*)d_in[4];
  float* out = (float*)d_out;

  bf16* ws = (bf16*)d_ws;
  const size_t WELEM = 1024u * 1024u;
  const size_t TELEM = 4096u * 1024u;
  bf16* wt  = ws;               // 4 transposed weights (8 MB)
  bf16* xbf = ws + 4 * WELEM;   // x bf16 (8 MB)
  bf16* q   = xbf + TELEM;      // q (z=0), k (z=1) via cStrideZ
  bf16* k   = q + TELEM;
  bf16* vt  = k + TELEM;        // V written pre-transposed by QKV epilogue
  bf16* ao  = vt + TELEM;

  const float QSCALE = 0.125f * 1.44269504088896340736f;  // 1/sqrt(64)*log2e

  prep<<<dim3(16, 16, 5), 256, 0, stream>>>(Wq, Wk, Wv, Wo, x, wt, xbf);
  gemm_bt<bf16, 2><<<dim3(16, 32, 3), 256, 0, stream>>>(
      xbf, wt, q, (int)WELEM, (int)TELEM, QSCALE, vt);
  attn_fwd<<<dim3(512), 512, 0, stream>>>(q, k, vt, ao);
  gemm_bt<float, 2><<<dim3(16, 32, 1), 256, 0, stream>>>(
      ao, wt + 3 * WELEM, out, 0, 0, 1.0f, nullptr);
}

// Round 13
// 175.258 us; speedup vs baseline: 1.1977x; 1.0875x over previous
//
#include <hip/hip_runtime.h>
#include <hip/hip_bf16.h>

typedef __bf16 bf16;
typedef __bf16 bf16x4 __attribute__((ext_vector_type(4)));
typedef __bf16 bf16x8 __attribute__((ext_vector_type(8)));
typedef float f32x4 __attribute__((ext_vector_type(4)));

#define MFMA16(a, b, c) __builtin_amdgcn_mfma_f32_16x16x32_bf16((a), (b), (c), 0, 0, 0)

// async global->LDS, 16B per lane; LDS dest = wave-uniform base + lane*16.
__device__ __forceinline__ void async16(const void* g, void* l) {
  typedef const unsigned int __attribute__((address_space(1))) * GP;
  typedef unsigned int __attribute__((address_space(3))) * LP;
  __builtin_amdgcn_global_load_lds((GP)g, (LP)l, 16, 0, 0);
}

// ---------------------------------------------------------------------------
// prep: z<4 -> transpose+convert weight z (fp32 [1024x1024] -> bf16 Wt[n][k]);
// z==4 -> convert x fp32 -> bf16. grid (16,16,5) x 256 threads.
// ---------------------------------------------------------------------------
__global__ __launch_bounds__(256) void prep(
    const float* __restrict__ w0, const float* __restrict__ w1,
    const float* __restrict__ w2, const float* __restrict__ w3,
    const float* __restrict__ x, bf16* __restrict__ wtOut,
    bf16* __restrict__ xOut) {
  const int t = threadIdx.x;
  if (blockIdx.z == 4) {  // x conversion
    size_t base = ((size_t)(blockIdx.y * 16 + blockIdx.x)) * 16384;
#pragma unroll
    for (int p = 0; p < 16; ++p) {
      size_t i = base + (size_t)(p * 256 + t) * 4;
      f32x4 v = *(const f32x4*)&x[i];
      bf16 o[4];
#pragma unroll
      for (int j = 0; j < 4; ++j) o[j] = (bf16)v[j];
      *(ulong1*)&xOut[i] = *(ulong1*)o;
    }
    return;
  }
  __shared__ __align__(16) float tile[64][68];
  const float* src = (blockIdx.z == 0) ? w0 : (blockIdx.z == 1) ? w1
                   : (blockIdx.z == 2) ? w2 : w3;
  bf16* dst = wtOut + (size_t)blockIdx.z * (1024u * 1024u);
  const int bx = blockIdx.x, by = blockIdx.y;
#pragma unroll
  for (int p = 0; p < 4; ++p) {
    int idx = t + p * 256;
    int r = idx >> 4, c4 = idx & 15;
    *(f32x4*)&tile[r][c4 * 4] =
        *(const f32x4*)&src[(size_t)(by * 64 + r) * 1024 + bx * 64 + c4 * 4];
  }
  __syncthreads();
#pragma unroll
  for (int p = 0; p < 2; ++p) {
    int idx = t + p * 256;
    int rn = idx >> 3, c8 = idx & 7;
    bf16x8 v;
#pragma unroll
    for (int i = 0; i < 8; ++i) v[i] = (bf16)tile[c8 * 8 + i][rn];
    *(bf16x8*)&dst[(size_t)(bx * 64 + rn) * 1024 + by * 64 + c8 * 8] = v;
  }
}

// ---------------------------------------------------------------------------
// GEMM: C[4096 x 1024] = A @ W (Bt[n][k]). Block tile 128 x (NI*32), BK=32
// double-buffered global_load_lds, one barrier per K-step.
// XCD-SWIZZLED 1D grid: bid = (y&7) + 8*(x + XT*(y>>3)) -> all x-blocks of
// an A-tile row share bid%8 (same XCD) => A re-reads hit L2 not HBM.
// z in grid.y (gridDim.x % 8 == 0 keeps residue classes).
// z==0 scaled by scaleZ0; z==2 with vtOut: fused V^T epilogue.
// ---------------------------------------------------------------------------
template <typename OutT, int NI>
__global__ __launch_bounds__(256, 4) void gemm_bt(
    const bf16* __restrict__ A, const bf16* __restrict__ Bt,
    OutT* __restrict__ C, int btStrideZ, int cStrideZ, float scaleZ0,
    bf16* __restrict__ vtOut) {
  constexpr int XT = 1024 / (NI * 32);  // x-tiles: 8 (NI=4) / 16 (NI=2)
  const int bid = blockIdx.x;
  const int rr = bid & 7, tt = bid >> 3;
  const int xb = tt % XT, yb = (tt / XT) * 8 + rr;
  const int zi = blockIdx.y;

  const int tid = threadIdx.x;
  const int wave = tid >> 6, lane = tid & 63;
  const int quad = lane >> 4, l16 = lane & 15;
  const int wm = wave >> 1, wn = wave & 1;
  const int m0 = yb * 128, n0 = xb * (NI * 32);
  const bf16* Bz = Bt + (size_t)zi * (size_t)btStrideZ;
  OutT* Cz = C + (size_t)zi * (size_t)cStrideZ;
  const float sc = (zi == 0) ? scaleZ0 : 1.0f;

  __shared__ __align__(16) bf16 lsA[2][128 * 32];
  __shared__ __align__(16) bf16 lsB[2][NI * 32 * 32];

  const int lrow = lane >> 2;
  const int cgX = (lane & 3) ^ ((lrow >> 1) & 3);
  const int fR = (l16 >> 1) & 3;

  f32x4 acc[4][NI];
#pragma unroll
  for (int i = 0; i < 4; ++i)
#pragma unroll
    for (int j = 0; j < NI; ++j) acc[i][j] = (f32x4){0.f, 0.f, 0.f, 0.f};

#pragma unroll
  for (int c = 0; c < 2; ++c) {
    int chunk = wave * 2 + c;
    int row = chunk * 16 + lrow;
    async16(&A[(size_t)(m0 + row) * 1024 + cgX * 8], &lsA[0][chunk * 512]);
  }
#pragma unroll
  for (int c = 0; c < NI / 2; ++c) {
    int chunk = wave * (NI / 2) + c;
    int row = chunk * 16 + lrow;
    async16(&Bz[(size_t)(n0 + row) * 1024 + cgX * 8], &lsB[0][chunk * 512]);
  }
  __syncthreads();

  for (int it = 0; it < 32; ++it) {
    const int cur = it & 1;
    if (it < 31) {
      int k0n = (it + 1) * 32;
#pragma unroll
      for (int c = 0; c < 2; ++c) {
        int chunk = wave * 2 + c;
        int row = chunk * 16 + lrow;
        async16(&A[(size_t)(m0 + row) * 1024 + k0n + cgX * 8],
                &lsA[cur ^ 1][chunk * 512]);
      }
#pragma unroll
      for (int c = 0; c < NI / 2; ++c) {
        int chunk = wave * (NI / 2) + c;
        int row = chunk * 16 + lrow;
        async16(&Bz[(size_t)(n0 + row) * 1024 + k0n + cgX * 8],
                &lsB[cur ^ 1][chunk * 512]);
      }
    }

    bf16x8 af[4], bfr[NI];
#pragma unroll
    for (int i = 0; i < 4; ++i) {
      int ra = wm * 64 + i * 16 + l16;
      af[i] = *(const bf16x8*)&lsA[cur][ra * 32 + ((quad ^ fR) * 8)];
    }
#pragma unroll
    for (int ni = 0; ni < NI; ++ni) {
      int rb = wn * (NI * 16) + ni * 16 + l16;
      bfr[ni] = *(const bf16x8*)&lsB[cur][rb * 32 + ((quad ^ fR) * 8)];
    }
#pragma unroll
    for (int mi = 0; mi < 4; ++mi)
#pragma unroll
      for (int ni = 0; ni < NI; ++ni)
        acc[mi][ni] = MFMA16(af[mi], bfr[ni], acc[mi][ni]);

    __syncthreads();
  }

  if (zi == 2 && vtOut != nullptr) {
    // V: write transposed per head -> vt[(b*16+h)][d][s], s contiguous in r
#pragma unroll
    for (int mi = 0; mi < 4; ++mi)
#pragma unroll
      for (int ni = 0; ni < NI; ++ni) {
        int col = n0 + wn * (NI * 16) + ni * 16 + l16;
        int h = col >> 6, d = col & 63;
        int row = m0 + wm * 64 + mi * 16 + quad * 4;
        int b = row >> 11, s = row & 2047;
        bf16 o[4];
#pragma unroll
        for (int r = 0; r < 4; ++r) o[r] = (bf16)acc[mi][ni][r];
        *(ulong1*)&vtOut[((size_t)(b * 16 + h) * 64 + d) * 2048 + s] =
            *(ulong1*)o;
      }
  } else {
#pragma unroll
    for (int mi = 0; mi < 4; ++mi)
#pragma unroll
      for (int ni = 0; ni < NI; ++ni) {
        int col = n0 + wn * (NI * 16) + ni * 16 + l16;
#pragma unroll
        for (int r = 0; r < 4; ++r) {
          int row = m0 + wm * 64 + mi * 16 + quad * 4 + r;
          Cz[(size_t)row * 1024 + col] = (OutT)(acc[mi][ni][r] * sc);
        }
      }
  }
}

// ---------------------------------------------------------------------------
// Flash attention v4 (round-12, unchanged): register-resident P.
// S^T = K Q^T; lane holds (key, q=l16) which is the PV A-frag pattern.
// K/V dbuf global_load_lds, one barrier per tile; LDS 32KB; grid 512 x 512thr.
// ---------------------------------------------------------------------------
__global__ __launch_bounds__(512, 4) void attn_fwd(
    const bf16* __restrict__ Q, const bf16* __restrict__ K,
    const bf16* __restrict__ Vt, bf16* __restrict__ O) {
  const int bid = blockIdx.x;
  const int x = bid & 15, hb = bid >> 4;
  const int h = hb & 15, b = hb >> 4;
  const int qt = b ? (15 - x) : x;
  const int tid = threadIdx.x;
  const int wave = tid >> 6, lane = tid & 63;
  const int quad = lane >> 4, l16 = lane & 15;

  __shared__ __align__(16) bf16 SMEM[16384];  // 32 KB
  const int kof[2] = {0, 8192};
  const int vof[2] = {4096, 12288};
  bf16* Qs = &SMEM[8192];

  const size_t base = ((size_t)b * 2048) * 1024 + (size_t)h * 64;
  const bf16* Qb = Q + base;
  const bf16* Kb = K + base;
  const bf16* Vtb = Vt + ((size_t)(b * 16 + h)) * 64 * 2048;
  bf16* Ob = O + base;

  const int lrow = lane >> 3;
  const int cgX = (lane & 7) ^ lrow;

#pragma unroll
  for (int c = 0; c < 2; ++c) {
    int chunk = wave * 2 + c;
    int row = chunk * 8 + lrow;
    async16(&Qb[(size_t)(qt * 128 + row) * 1024 + cgX * 8], &Qs[chunk * 512]);
  }
  {
    int row = wave * 8 + lrow;
    async16(&Kb[(size_t)row * 1024 + cgX * 8], &SMEM[kof[0] + wave * 512]);
    async16(&Vtb[(size_t)row * 2048 + cgX * 8], &SMEM[vof[0] + wave * 512]);
  }
  __syncthreads();

  bf16x8 aq[2];
#pragma unroll
  for (int ks = 0; ks < 2; ++ks) {
    int row = wave * 16 + l16;
    aq[ks] = *(const bf16x8*)&Qs[row * 64 + (((ks * 4 + quad) ^ (l16 & 7)) * 8)];
  }
  __syncthreads();  // Q-frag reads done before buf1 (Q overlay) is written

  const float NEG_INF = -__builtin_inff();
  float ls_acc = 0.f;
  f32x4 Oacc[4];
#pragma unroll
  for (int nt = 0; nt < 4; ++nt) Oacc[nt] = (f32x4){0.f, 0.f, 0.f, 0.f};

  const int kt_end = 2 * qt + 1;
  const int ktd = 2 * qt + (wave >> 2);

  for (int kt = 0; kt <= kt_end; ++kt) {
    const int cur = kt & 1;
    if (kt < kt_end) {
      int row = wave * 8 + lrow;
      async16(&Kb[(size_t)((kt + 1) * 64 + row) * 1024 + cgX * 8],
              &SMEM[kof[cur ^ 1] + wave * 512]);
      async16(&Vtb[(size_t)row * 2048 + (kt + 1) * 64 + cgX * 8],
              &SMEM[vof[cur ^ 1] + wave * 512]);
    }

    if (kt <= ktd) {
      f32x4 sv[4];
#pragma unroll
      for (int nt = 0; nt < 4; ++nt) {
        int row = nt * 16 + l16;
        bf16x8 bk0 = *(const bf16x8*)&SMEM[kof[cur] + row * 64 +
                                           ((quad ^ (l16 & 7)) * 8)];
        bf16x8 bk1 = *(const bf16x8*)&SMEM[kof[cur] + row * 64 +
                                           (((4 + quad) ^ (l16 & 7)) * 8)];
        sv[nt] = (f32x4){0.f, 0.f, 0.f, 0.f};
        sv[nt] = MFMA16(bk0, aq[0], sv[nt]);
        sv[nt] = MFMA16(bk1, aq[1], sv[nt]);
      }

      if (kt == ktd) {
        const int q_rel = wave * 16 + l16;
        const int cb = (kt - 2 * qt) * 64;
#pragma unroll
        for (int nt = 0; nt < 4; ++nt) {
          const int kb = cb + nt * 16 + quad * 4;
#pragma unroll
          for (int r = 0; r < 4; ++r)
            if (kb + r > q_rel) sv[nt][r] = NEG_INF;
        }
      }

      bf16x8 apf[2];
#pragma unroll
      for (int a = 0; a < 2; ++a)
#pragma unroll
        for (int g = 0; g < 2; ++g)
#pragma unroll
          for (int r = 0; r < 4; ++r) {
            float p = exp2f(sv[a * 2 + g][r]);
            ls_acc += p;
            apf[a][g * 4 + r] = (bf16)p;
          }

#pragma unroll
      for (int nt = 0; nt < 4; ++nt) {
        const int R = nt * 16 + l16;
        const int sub = (quad & 1) * 4;
#pragma unroll
        for (int a = 0; a < 2; ++a) {
          const int g0 = a * 4 + (quad >> 1);
          const int g1 = g0 + 2;
          bf16x4 lo = *(const bf16x4*)&SMEM[vof[cur] + R * 64 +
                                            ((g0 ^ (l16 & 7)) * 8) + sub];
          bf16x4 hi = *(const bf16x4*)&SMEM[vof[cur] + R * 64 +
                                            ((g1 ^ (l16 & 7)) * 8) + sub];
          bf16x8 bvf;
#pragma unroll
          for (int i = 0; i < 4; ++i) {
            bvf[i] = lo[i];
            bvf[4 + i] = hi[i];
          }
          Oacc[nt] = MFMA16(apf[a], bvf, Oacc[nt]);
        }
      }
    }

    __syncthreads();
  }

  ls_acc += __shfl_xor(ls_acc, 16, 64);
  ls_acc += __shfl_xor(ls_acc, 32, 64);
  float rl[4];
#pragma unroll
  for (int r = 0; r < 4; ++r) rl[r] = 1.f / __shfl(ls_acc, quad * 4 + r, 64);
#pragma unroll
  for (int nt = 0; nt < 4; ++nt)
#pragma unroll
    for (int r = 0; r < 4; ++r) {
      int row = qt * 128 + wave * 16 + quad * 4 + r;
      Ob[(size_t)row * 1024 + nt * 16 + l16] = (bf16)(Oacc[nt][r] * rl[r]);
    }
}

// ---------------------------------------------------------------------------
// Launch
// ---------------------------------------------------------------------------
extern "C" void kernel_launch(void* const* d_in, const int* in_sizes, int n_in,
                              void* d_out, int out_size, void* d_ws,
                              size_t ws_size, hipStream_t stream) {
  (void)in_sizes; (void)n_in; (void)out_size; (void)ws_size;
  const float* x  = (const float*)d_in[0];
  const float* Wq = (const float*)d_in[1];
  const float* Wk = (const float*)d_in[2];
  const float* Wv = (const float*)d_in[3];
  const float* Wo = (const float*)d_in[4];
  float* out = (float*)d_out;

  bf16* ws = (bf16*)d_ws;
  const size_t WELEM = 1024u * 1024u;
  const size_t TELEM = 4096u * 1024u;
  bf16* wt  = ws;               // 4 transposed weights (8 MB)
  bf16* xbf = ws + 4 * WELEM;   // x bf16 (8 MB)
  bf16* q   = xbf + TELEM;      // q (z=0), k (z=1) via cStrideZ
  bf16* k   = q + TELEM;
  bf16* vt  = k + TELEM;        // V written pre-transposed by QKV epilogue
  bf16* ao  = vt + TELEM;

  const float QSCALE = 0.125f * 1.44269504088896340736f;  // 1/sqrt(64)*log2e

  prep<<<dim3(16, 16, 5), 256, 0, stream>>>(Wq, Wk, Wv, Wo, x, wt, xbf);
  // QKV: NI=4 -> 128x128 tiles, swizzled 1D grid 256 per z, z in grid.y
  gemm_bt<bf16, 4><<<dim3(256, 3), 256, 0, stream>>>(
      xbf, wt, q, (int)WELEM, (int)TELEM, QSCALE, vt);
  attn_fwd<<<dim3(512), 512, 0, stream>>>(q, k, vt, ao);
  // proj: NI=2 -> 128x64 tiles, swizzled 1D grid 512
  gemm_bt<float, 2><<<dim3(512, 1), 256, 0, stream>>>(
      ao, wt + 3 * WELEM, out, 0, 0, 1.0f, nullptr);
}